// Round 1
// baseline (169.438 us; speedup 1.0000x reference)
//
#include <hip/hip_runtime.h>

// Problem constants (fixed by setup_inputs)
#define B_      8
#define C_      512
#define L_      4096
#define WC_     64
#define KS_     7
#define GROUPS_ 8          // C_/WC_
#define PAD_    3          // (KS_-1)/2
#define LTILE_  1024
#define NTILES_ 4          // L_/LTILE_

// out[b,c,l] = sum_k x[b,c,l+k-3] * w[b, c/GROUPS_, k, l]
// One block per (b, wc, l-tile); block computes all GROUPS_ channels of the
// group so the w fragment is loaded once from HBM and reused 8x in registers.
__global__ __launch_bounds__(256)
void SKA_40106404610132_kernel(const float* __restrict__ x,
                               const float* __restrict__ w,
                               float* __restrict__ out) {
    const int bid  = blockIdx.x;
    const int tile = bid % NTILES_;
    const int bwc  = bid / NTILES_;     // b*WC_ + wc
    const int wc   = bwc % WC_;
    const int b    = bwc / WC_;
    const int t    = threadIdx.x;
    const int l0   = tile * LTILE_ + t * 4;   // this thread's 4 output cols

    // ---- load w[b, wc, k, l0..l0+3] for k=0..6 into registers (28 floats)
    const float* wbase = w + ((size_t)(b * WC_ + wc) * KS_) * L_ + l0;
    float wv[KS_][4];
    #pragma unroll
    for (int k = 0; k < KS_; ++k) {
        float4 f = *reinterpret_cast<const float4*>(wbase + (size_t)k * L_);
        wv[k][0] = f.x; wv[k][1] = f.y; wv[k][2] = f.z; wv[k][3] = f.w;
    }

    const size_t grp_off = (size_t)(b * C_ + wc * GROUPS_) * L_;
    const float* xgrp = x   + grp_off;
    float*       ogrp = out + grp_off;

    const bool lo_ok = (l0 >= 4);          // can load x[l0-4 .. l0-1]
    const bool hi_ok = (l0 + 8 <= L_);     // can load x[l0+4 .. l0+7]

    #pragma unroll
    for (int g = 0; g < GROUPS_; ++g) {
        const float* xrow = xgrp + (size_t)g * L_;

        // xv[i] = x[l0 - 4 + i], i in [0,12); out-of-range -> 0 (zero pad)
        float xv[12];
        {
            float4 m = *reinterpret_cast<const float4*>(xrow + l0);
            xv[4] = m.x; xv[5] = m.y; xv[6] = m.z; xv[7] = m.w;
        }
        if (lo_ok) {
            float4 lo = *reinterpret_cast<const float4*>(xrow + l0 - 4);
            xv[0] = lo.x; xv[1] = lo.y; xv[2] = lo.z; xv[3] = lo.w;
        } else {
            // l0 == 0: x[-4..-1] are in the zero-pad region
            xv[0] = 0.f; xv[1] = 0.f; xv[2] = 0.f; xv[3] = 0.f;
        }
        if (hi_ok) {
            float4 hi = *reinterpret_cast<const float4*>(xrow + l0 + 4);
            xv[8] = hi.x; xv[9] = hi.y; xv[10] = hi.z; xv[11] = hi.w;
        } else {
            // l0 == L_-4: x[L_ .. L_+3] are zero-pad
            xv[8] = 0.f; xv[9] = 0.f; xv[10] = 0.f; xv[11] = 0.f;
        }

        // out[l0+j] = sum_k xv[j+k+1] * wv[k][j]
        float acc[4];
        #pragma unroll
        for (int j = 0; j < 4; ++j) {
            float s = xv[j + 1] * wv[0][j];
            #pragma unroll
            for (int k = 1; k < KS_; ++k)
                s = fmaf(xv[j + k + 1], wv[k][j], s);
            acc[j] = s;
        }

        *reinterpret_cast<float4*>(ogrp + (size_t)g * L_ + l0) =
            make_float4(acc[0], acc[1], acc[2], acc[3]);
    }
}

extern "C" void kernel_launch(void* const* d_in, const int* in_sizes, int n_in,
                              void* d_out, int out_size, void* d_ws, size_t ws_size,
                              hipStream_t stream) {
    const float* x = (const float*)d_in[0];
    const float* w = (const float*)d_in[1];
    float* out = (float*)d_out;

    const int grid = B_ * WC_ * NTILES_;   // 2048 blocks
    SKA_40106404610132_kernel<<<grid, 256, 0, stream>>>(x, w, out);
}

// Round 3
// 167.900 us; speedup vs baseline: 1.0092x; 1.0092x over previous
//
#include <hip/hip_runtime.h>

// Problem constants (fixed by setup_inputs)
#define B_      8
#define C_      512
#define L_      4096
#define WC_     64
#define KS_     7
#define GROUPS_ 8          // C_/WC_
#define LTILE_  1024
#define NTILES_ 4          // L_/LTILE_
#define CPT_    2          // channels per thread (w reg-reuse factor)

// out[b,c,l] = sum_k x[b,c,l+k-3] * w[b, c/GROUPS_, k, l]
// One block per (b, wc, group-pair, l-tile). Each thread computes 4 outputs
// for 2 channels sharing the same w fragment. All 13 float4 loads are issued
// as independent named vectors BEFORE any use -> 13 outstanding vmem ops per
// thread (MLP), instead of the serialized per-group reload pattern R0's
// 28-VGPR codegen produced. launch_bounds(256,4) allows up to ~128 VGPRs.
__global__ __launch_bounds__(256, 4)
void SKA_40106404610132_kernel(const float* __restrict__ x,
                               const float* __restrict__ w,
                               float* __restrict__ out) {
    const int bid  = blockIdx.x;
    const int tile = bid & (NTILES_ - 1);          // 2 bits
    const int gp   = (bid >> 2) & 3;               // group-pair 0..3
    const int bwc  = bid >> 4;                     // b*WC_ + wc
    const int wc   = bwc & (WC_ - 1);
    const int b    = bwc >> 6;
    const int t    = threadIdx.x;
    const int l0   = tile * LTILE_ + t * 4;        // this thread's 4 cols

    // ---- issue all loads up front (independent -> overlapped latency) ----
    const float* wbase = w + ((size_t)(b * WC_ + wc) * KS_) * L_ + l0;
    const float4 wq0 = *reinterpret_cast<const float4*>(wbase + 0 * L_);
    const float4 wq1 = *reinterpret_cast<const float4*>(wbase + 1 * L_);
    const float4 wq2 = *reinterpret_cast<const float4*>(wbase + 2 * L_);
    const float4 wq3 = *reinterpret_cast<const float4*>(wbase + 3 * L_);
    const float4 wq4 = *reinterpret_cast<const float4*>(wbase + 4 * L_);
    const float4 wq5 = *reinterpret_cast<const float4*>(wbase + 5 * L_);
    const float4 wq6 = *reinterpret_cast<const float4*>(wbase + 6 * L_);

    const int c0 = wc * GROUPS_ + gp * CPT_;
    const float* xr0 = x + (size_t)(b * C_ + c0) * L_;
    const float* xr1 = xr0 + L_;

    const bool lo_ok = (l0 >= 4);
    const bool hi_ok = (l0 + 8 <= L_);
    const float4 z4 = make_float4(0.f, 0.f, 0.f, 0.f);

    const float4 a_lo = lo_ok ? *reinterpret_cast<const float4*>(xr0 + l0 - 4) : z4;
    const float4 a_md =         *reinterpret_cast<const float4*>(xr0 + l0);
    const float4 a_hi = hi_ok ? *reinterpret_cast<const float4*>(xr0 + l0 + 4) : z4;
    const float4 b_lo = lo_ok ? *reinterpret_cast<const float4*>(xr1 + l0 - 4) : z4;
    const float4 b_md =         *reinterpret_cast<const float4*>(xr1 + l0);
    const float4 b_hi = hi_ok ? *reinterpret_cast<const float4*>(xr1 + l0 + 4) : z4;

    // ---- w fragment to a statically-indexed array (SROA -> registers) ----
    float wv[KS_][4];
    #define WSET(k, q) wv[k][0] = q.x; wv[k][1] = q.y; wv[k][2] = q.z; wv[k][3] = q.w
    WSET(0, wq0); WSET(1, wq1); WSET(2, wq2); WSET(3, wq3);
    WSET(4, wq4); WSET(5, wq5); WSET(6, wq6);
    #undef WSET

    float* or0 = out + (size_t)(b * C_ + c0) * L_;
    float* or1 = or0 + L_;

    #define CONV_STORE(lo, md, hi, orow)                                     \
    {                                                                        \
        float xe[12];                                                        \
        xe[0] = lo.x; xe[1] = lo.y; xe[2]  = lo.z; xe[3]  = lo.w;            \
        xe[4] = md.x; xe[5] = md.y; xe[6]  = md.z; xe[7]  = md.w;            \
        xe[8] = hi.x; xe[9] = hi.y; xe[10] = hi.z; xe[11] = hi.w;            \
        float acc[4];                                                        \
        _Pragma("unroll")                                                    \
        for (int j = 0; j < 4; ++j) {                                        \
            float s = xe[j + 1] * wv[0][j];                                  \
            _Pragma("unroll")                                                \
            for (int k = 1; k < KS_; ++k)                                    \
                s = fmaf(xe[j + k + 1], wv[k][j], s);                        \
            acc[j] = s;                                                      \
        }                                                                    \
        *reinterpret_cast<float4*>(orow + l0) =                              \
            make_float4(acc[0], acc[1], acc[2], acc[3]);                     \
    }

    CONV_STORE(a_lo, a_md, a_hi, or0);
    CONV_STORE(b_lo, b_md, b_hi, or1);
    #undef CONV_STORE
}

extern "C" void kernel_launch(void* const* d_in, const int* in_sizes, int n_in,
                              void* d_out, int out_size, void* d_ws, size_t ws_size,
                              hipStream_t stream) {
    const float* x = (const float*)d_in[0];
    const float* w = (const float*)d_in[1];
    float* out = (float*)d_out;

    const int grid = B_ * WC_ * (GROUPS_ / CPT_) * NTILES_;   // 8192 blocks
    SKA_40106404610132_kernel<<<grid, 256, 0, stream>>>(x, w, out);
}